// Round 1
// baseline (704.653 us; speedup 1.0000x reference)
//
#include <hip/hip_runtime.h>
#include <cstddef>

#define N_NODES  50000
#define N_EDGES  800000
#define HDIM     128
#define SSUB     5000
#define GGRAPH   64

// ---------------------------------------------------------------------------
// CSR build: histogram of dst, exclusive scan -> rowptr, then fill src lists.
// ---------------------------------------------------------------------------

__global__ __launch_bounds__(256) void k_hist(const int* __restrict__ dst,
                                              int* __restrict__ cnt) {
    int e = blockIdx.x * 256 + threadIdx.x;   // grid = E/256 exact
    atomicAdd(&cnt[dst[e]], 1);
}

__global__ __launch_bounds__(256) void k_scan_reduce(const int* __restrict__ cnt,
                                                     int* __restrict__ bsum) {
    __shared__ int sd[256];
    int idx = blockIdx.x * 256 + threadIdx.x;
    int t = threadIdx.x;
    sd[t] = (idx < N_NODES) ? cnt[idx] : 0;
    __syncthreads();
    for (int off = 128; off > 0; off >>= 1) {
        if (t < off) sd[t] += sd[t + off];
        __syncthreads();
    }
    if (t == 0) bsum[blockIdx.x] = sd[0];
}

__global__ __launch_bounds__(256) void k_scan_top(const int* __restrict__ bsum,
                                                  int* __restrict__ boff, int nb) {
    __shared__ int sd[256];
    int t = threadIdx.x;
    sd[t] = (t < nb) ? bsum[t] : 0;
    __syncthreads();
    for (int off = 1; off < 256; off <<= 1) {
        int v = (t >= off) ? sd[t - off] : 0;
        __syncthreads();
        sd[t] += v;
        __syncthreads();
    }
    boff[t] = (t == 0) ? 0 : sd[t - 1];   // exclusive block offsets
}

__global__ __launch_bounds__(256) void k_scan_final(const int* __restrict__ cnt,
                                                    const int* __restrict__ boff,
                                                    int* __restrict__ rowptr) {
    __shared__ int sd[256];
    int idx = blockIdx.x * 256 + threadIdx.x;
    int t = threadIdx.x;
    int v = (idx < N_NODES) ? cnt[idx] : 0;
    sd[t] = v;
    __syncthreads();
    for (int off = 1; off < 256; off <<= 1) {
        int u = (t >= off) ? sd[t - off] : 0;
        __syncthreads();
        sd[t] += u;
        __syncthreads();
    }
    if (idx < N_NODES) rowptr[idx] = sd[t] - v + boff[blockIdx.x];  // exclusive
    if (idx == 0) rowptr[N_NODES] = N_EDGES;
}

__global__ __launch_bounds__(256) void k_fill(const int* __restrict__ src,
                                              const int* __restrict__ dst,
                                              const int* __restrict__ rowptr,
                                              int* __restrict__ cur,
                                              int* __restrict__ csrc) {
    int e = blockIdx.x * 256 + threadIdx.x;   // grid = E/256 exact
    int d = dst[e];
    int pos = rowptr[d] + atomicAdd(&cur[d], 1);
    csrc[pos] = src[e];
}

// ---------------------------------------------------------------------------
// Conv 1 front: aggregate x (F_IN=2) and apply W1a (2x128) + bias + relu.
// ---------------------------------------------------------------------------

__global__ __launch_bounds__(256) void k_aggr0(const float2* __restrict__ x,
                                               const int* __restrict__ rowptr,
                                               const int* __restrict__ csrc,
                                               float2* __restrict__ t0) {
    int n = blockIdx.x * 256 + threadIdx.x;
    if (n >= N_NODES) return;
    int s = rowptr[n], e = rowptr[n + 1];
    float2 a0 = x[n];
    float2 a1 = make_float2(0.f, 0.f);
    int k = s;
    for (; k + 1 < e; k += 2) {
        float2 v0 = x[csrc[k]];
        float2 v1 = x[csrc[k + 1]];
        a0.x += v0.x; a0.y += v0.y;
        a1.x += v1.x; a1.y += v1.y;
    }
    if (k < e) { float2 v = x[csrc[k]]; a0.x += v.x; a0.y += v.y; }
    t0[n] = make_float2(a0.x + a1.x, a0.y + a1.y);
}

__global__ __launch_bounds__(256) void k_lin1a(const float2* __restrict__ t0,
                                               const float* __restrict__ W1a,
                                               const float* __restrict__ b1a,
                                               float* __restrict__ out) {
    int gid = blockIdx.x * 256 + threadIdx.x;   // grid = N*128/256 exact
    int n = gid >> 7, j = gid & 127;
    float2 t = t0[n];
    float v = fmaf(t.x, W1a[j], fmaf(t.y, W1a[128 + j], b1a[j]));
    out[gid] = fmaxf(v, 0.f);
}

// ---------------------------------------------------------------------------
// GIN aggregation, H=128: one wave per node, lane holds float2 (2 features).
// out[n] = h[n] + sum_{src in-edges} h[src]
// ---------------------------------------------------------------------------

__global__ __launch_bounds__(256) void k_aggr128(const float2* __restrict__ h,
                                                 const int* __restrict__ rowptr,
                                                 const int* __restrict__ csrc,
                                                 float2* __restrict__ out) {
    int node = blockIdx.x * 4 + (threadIdx.x >> 6);   // grid = N/4 exact
    int lane = threadIdx.x & 63;
    int s = rowptr[node], e = rowptr[node + 1];
    float2 a0 = h[(size_t)node * 64 + lane];
    float2 a1 = make_float2(0.f, 0.f);
    int k = s;
    for (; k + 1 < e; k += 2) {
        int s0 = csrc[k], s1 = csrc[k + 1];
        float2 v0 = h[(size_t)s0 * 64 + lane];
        float2 v1 = h[(size_t)s1 * 64 + lane];
        a0.x += v0.x; a0.y += v0.y;
        a1.x += v1.x; a1.y += v1.y;
    }
    if (k < e) {
        float2 v = h[(size_t)csrc[k] * 64 + lane];
        a0.x += v.x; a0.y += v.y;
    }
    out[(size_t)node * 64 + lane] = make_float2(a0.x + a1.x, a0.y + a1.y);
}

// ---------------------------------------------------------------------------
// fp32 GEMM: C[n][j] = relu(sum_k A[n][k] * W[k][j] + bias[j]), K=128, cols=128.
// 128-row tile per block, k-chunks of 32 in LDS, 8x8 micro-tile per thread.
// ---------------------------------------------------------------------------

__global__ __launch_bounds__(256) void k_gemm128(const float* __restrict__ A,
                                                 const float* __restrict__ W,
                                                 const float* __restrict__ bias,
                                                 float* __restrict__ C, int nrows) {
    __shared__ float As[32][128];   // k-major: As[kk][row]
    __shared__ float Ws[32][128];   // k-major: Ws[kk][col] (same layout as W)
    const int tid = threadIdx.x;
    const int tx = tid & 15;        // col group: cols 8*tx..8*tx+7
    const int ty = tid >> 4;        // row group: rows 8*ty..8*ty+7
    const int rowBase = blockIdx.x << 7;
    float acc[8][8];
#pragma unroll
    for (int i = 0; i < 8; ++i)
#pragma unroll
        for (int j = 0; j < 8; ++j) acc[i][j] = 0.f;

    const int r  = tid >> 1;          // staging row (0..127)
    const int k0 = (tid & 1) << 4;    // staging k half (0 or 16)
    const int grow = rowBase + r;

    for (int kc = 0; kc < 128; kc += 32) {
        float4 av[4];
        if (grow < nrows) {
            const float4* Ap = (const float4*)(A + (size_t)grow * 128 + kc + k0);
#pragma unroll
            for (int q = 0; q < 4; ++q) av[q] = Ap[q];
        } else {
#pragma unroll
            for (int q = 0; q < 4; ++q) av[q] = make_float4(0.f, 0.f, 0.f, 0.f);
        }
        float4 wv[4];
        const float4* Wp = (const float4*)(W + (size_t)kc * 128);
#pragma unroll
        for (int q = 0; q < 4; ++q) wv[q] = Wp[tid * 4 + q];
        __syncthreads();   // previous chunk's compute done before overwrite
#pragma unroll
        for (int q = 0; q < 4; ++q) {   // transpose A into k-major
            As[k0 + q * 4 + 0][r] = av[q].x;
            As[k0 + q * 4 + 1][r] = av[q].y;
            As[k0 + q * 4 + 2][r] = av[q].z;
            As[k0 + q * 4 + 3][r] = av[q].w;
        }
#pragma unroll
        for (int q = 0; q < 4; ++q) ((float4*)Ws)[tid * 4 + q] = wv[q];
        __syncthreads();
#pragma unroll 4
        for (int kk = 0; kk < 32; ++kk) {
            float a[8], w[8];
            *(float4*)&a[0] = *(const float4*)&As[kk][ty * 8];
            *(float4*)&a[4] = *(const float4*)&As[kk][ty * 8 + 4];
            *(float4*)&w[0] = *(const float4*)&Ws[kk][tx * 8];
            *(float4*)&w[4] = *(const float4*)&Ws[kk][tx * 8 + 4];
#pragma unroll
            for (int i = 0; i < 8; ++i)
#pragma unroll
                for (int j = 0; j < 8; ++j)
                    acc[i][j] = fmaf(a[i], w[j], acc[i][j]);
        }
    }
    float bv[8];
#pragma unroll
    for (int j = 0; j < 8; ++j) bv[j] = bias[tx * 8 + j];
#pragma unroll
    for (int i = 0; i < 8; ++i) {
        int row = rowBase + ty * 8 + i;
        if (row < nrows) {
            float o[8];
#pragma unroll
            for (int j = 0; j < 8; ++j) o[j] = fmaxf(acc[i][j] + bv[j], 0.f);
            *(float4*)(C + (size_t)row * 128 + tx * 8)     = *(float4*)&o[0];
            *(float4*)(C + (size_t)row * 128 + tx * 8 + 4) = *(float4*)&o[4];
        }
    }
}

// ---------------------------------------------------------------------------
// Pooling: node -> subgraph -> graph (atomic fadd, accumulators L2-resident).
// ---------------------------------------------------------------------------

__global__ __launch_bounds__(256) void k_pool1(const float* __restrict__ h,
                                               const int* __restrict__ n2s,
                                               float* __restrict__ poolS) {
    int gid = blockIdx.x * 256 + threadIdx.x;   // grid = N*128/256 exact
    int n = gid >> 7, j = gid & 127;
    atomicAdd(&poolS[(size_t)n2s[n] * 128 + j], h[gid]);
}

__global__ __launch_bounds__(256) void k_pool2(const float* __restrict__ poolS,
                                               const int* __restrict__ s2g,
                                               float* __restrict__ poolG) {
    int gid = blockIdx.x * 256 + threadIdx.x;   // grid = S*128/256 exact
    int s = gid >> 7, j = gid & 127;
    atomicAdd(&poolG[(size_t)s2g[s] * 128 + j], poolS[gid]);
}

// ---------------------------------------------------------------------------
// Final MLP + log_softmax: one block per graph (G=64), 128 threads.
// ---------------------------------------------------------------------------

__global__ __launch_bounds__(128) void k_final(const float* __restrict__ poolG,
                                               const float* __restrict__ W1,
                                               const float* __restrict__ b1,
                                               const float* __restrict__ W2,
                                               const float* __restrict__ b2,
                                               float* __restrict__ out) {
    __shared__ float row[128];
    __shared__ float t1[128];
    __shared__ float red[128];
    int g = blockIdx.x, j = threadIdx.x;
    row[j] = poolG[g * 128 + j];
    __syncthreads();
    float s = b1[j];
    for (int k = 0; k < 128; ++k) s = fmaf(row[k], W1[k * 128 + j], s);
    t1[j] = fmaxf(s, 0.f);
    __syncthreads();
    float s2 = b2[j];
    for (int k = 0; k < 128; ++k) s2 = fmaf(t1[k], W2[k * 128 + j], s2);
    red[j] = s2;
    __syncthreads();
    for (int off = 64; off > 0; off >>= 1) {
        if (j < off) red[j] = fmaxf(red[j], red[j + off]);
        __syncthreads();
    }
    float m = red[0];
    __syncthreads();
    red[j] = expf(s2 - m);
    __syncthreads();
    for (int off = 64; off > 0; off >>= 1) {
        if (j < off) red[j] += red[j + off];
        __syncthreads();
    }
    float lse = m + logf(red[0]);
    out[g * 128 + j] = s2 - lse;
}

// ---------------------------------------------------------------------------

extern "C" void kernel_launch(void* const* d_in, const int* in_sizes, int n_in,
                              void* d_out, int out_size, void* d_ws, size_t ws_size,
                              hipStream_t stream) {
    (void)in_sizes; (void)n_in; (void)out_size; (void)ws_size;
    const float* x    = (const float*)d_in[0];
    const int*   ei   = (const int*)d_in[1];
    const int*   n2s  = (const int*)d_in[2];
    const int*   s2g  = (const int*)d_in[3];
    const float* W1a  = (const float*)d_in[4];
    const float* b1a  = (const float*)d_in[5];
    const float* W1b  = (const float*)d_in[6];
    const float* b1b  = (const float*)d_in[7];
    const float* cWa  = (const float*)d_in[8];
    const float* cba  = (const float*)d_in[9];
    const float* cWb  = (const float*)d_in[10];
    const float* cbb  = (const float*)d_in[11];
    const float* l1W  = (const float*)d_in[12];
    const float* l1b  = (const float*)d_in[13];
    const float* l2W  = (const float*)d_in[14];
    const float* l2b  = (const float*)d_in[15];
    float* out = (float*)d_out;

    // workspace layout (~58 MB)
    float* hX     = (float*)d_ws;                       // N*128 fp32
    float* hY     = hX + (size_t)N_NODES * HDIM;        // N*128 fp32
    float* t0     = hY + (size_t)N_NODES * HDIM;        // N*2 fp32
    int*   rowptr = (int*)(t0 + (size_t)N_NODES * 2);   // N+2 (padded)
    int*   cnt    = rowptr + (N_NODES + 2);             // N
    int*   bsum   = cnt + N_NODES;                      // 256
    int*   boff   = bsum + 256;                         // 256
    int*   csrc   = boff + 256;                         // E
    float* poolS  = (float*)(csrc + N_EDGES);           // S*128
    float* poolG  = poolS + (size_t)SSUB * HDIM;        // G*128

    const int* srcA = ei;
    const int* dstA = ei + N_EDGES;
    const int nScanBlocks = (N_NODES + 255) / 256;      // 196

    // --- CSR build ---
    hipMemsetAsync(cnt, 0, N_NODES * sizeof(int), stream);
    hipMemsetAsync(poolS, 0, (size_t)(SSUB + GGRAPH) * HDIM * sizeof(float), stream);
    k_hist<<<N_EDGES / 256, 256, 0, stream>>>(dstA, cnt);
    k_scan_reduce<<<nScanBlocks, 256, 0, stream>>>(cnt, bsum);
    k_scan_top<<<1, 256, 0, stream>>>(bsum, boff, nScanBlocks);
    k_scan_final<<<nScanBlocks, 256, 0, stream>>>(cnt, boff, rowptr);
    hipMemsetAsync(cnt, 0, N_NODES * sizeof(int), stream);
    k_fill<<<N_EDGES / 256, 256, 0, stream>>>(srcA, dstA, rowptr, cnt, csrc);

    // --- conv 1 ---
    k_aggr0<<<nScanBlocks, 256, 0, stream>>>((const float2*)x, rowptr, csrc, (float2*)t0);
    k_lin1a<<<(N_NODES * HDIM) / 256, 256, 0, stream>>>((const float2*)t0, W1a, b1a, hX);
    k_gemm128<<<(N_NODES + 127) / 128, 256, 0, stream>>>(hX, W1b, b1b, hY, N_NODES);

    // --- convs 2..4 (ping-pong: h in bufA at loop top) ---
    float* bufA = hY;
    float* bufB = hX;
    for (int i = 0; i < 3; ++i) {
        k_aggr128<<<N_NODES / 4, 256, 0, stream>>>((const float2*)bufA, rowptr, csrc,
                                                   (float2*)bufB);
        k_gemm128<<<(N_NODES + 127) / 128, 256, 0, stream>>>(bufB, cWa + (size_t)i * HDIM * HDIM,
                                                             cba + i * HDIM, bufA, N_NODES);
        k_gemm128<<<(N_NODES + 127) / 128, 256, 0, stream>>>(bufA, cWb + (size_t)i * HDIM * HDIM,
                                                             cbb + i * HDIM, bufB, N_NODES);
        float* tmp = bufA; bufA = bufB; bufB = tmp;   // h now in bufA
    }

    // --- pooling + head ---
    k_pool1<<<(N_NODES * HDIM) / 256, 256, 0, stream>>>(bufA, n2s, poolS);
    k_pool2<<<(SSUB * HDIM) / 256, 256, 0, stream>>>(poolS, s2g, poolG);
    k_final<<<GGRAPH, 128, 0, stream>>>(poolG, l1W, l1b, l2W, l2b, out);
}

// Round 2
// 603.355 us; speedup vs baseline: 1.1679x; 1.1679x over previous
//
#include <hip/hip_runtime.h>
#include <cstddef>

#define N_NODES  50000
#define N_EDGES  800000
#define HDIM     128
#define SSUB     5000
#define GGRAPH   64

typedef unsigned int uint;
typedef unsigned short ushort;

// bf16x2 helpers (packed in a uint: low ushort = even feature, high = odd)
__device__ __forceinline__ float bflo(uint v) { return __uint_as_float(v << 16); }
__device__ __forceinline__ float bfhi(uint v) { return __uint_as_float(v & 0xffff0000u); }
__device__ __forceinline__ uint packbf(float lo, float hi) {
    uint a = __float_as_uint(lo), b = __float_as_uint(hi);
    a = (a + 0x7fff + ((a >> 16) & 1)) >> 16;          // RNE
    b = (b + 0x7fff + ((b >> 16) & 1)) & 0xffff0000u;  // RNE, keep high half
    return a | b;
}

// ---------------------------------------------------------------------------
// CSR build: histogram of dst, exclusive scan -> rowptr, then fill src lists.
// ---------------------------------------------------------------------------

__global__ __launch_bounds__(256) void k_hist(const int* __restrict__ dst,
                                              int* __restrict__ cnt) {
    int e = blockIdx.x * 256 + threadIdx.x;   // grid = E/256 exact
    atomicAdd(&cnt[dst[e]], 1);
}

__global__ __launch_bounds__(256) void k_scan_reduce(const int* __restrict__ cnt,
                                                     int* __restrict__ bsum) {
    __shared__ int sd[256];
    int idx = blockIdx.x * 256 + threadIdx.x;
    int t = threadIdx.x;
    sd[t] = (idx < N_NODES) ? cnt[idx] : 0;
    __syncthreads();
    for (int off = 128; off > 0; off >>= 1) {
        if (t < off) sd[t] += sd[t + off];
        __syncthreads();
    }
    if (t == 0) bsum[blockIdx.x] = sd[0];
}

__global__ __launch_bounds__(256) void k_scan_top(const int* __restrict__ bsum,
                                                  int* __restrict__ boff, int nb) {
    __shared__ int sd[256];
    int t = threadIdx.x;
    sd[t] = (t < nb) ? bsum[t] : 0;
    __syncthreads();
    for (int off = 1; off < 256; off <<= 1) {
        int v = (t >= off) ? sd[t - off] : 0;
        __syncthreads();
        sd[t] += v;
        __syncthreads();
    }
    boff[t] = (t == 0) ? 0 : sd[t - 1];   // exclusive block offsets
}

__global__ __launch_bounds__(256) void k_scan_final(const int* __restrict__ cnt,
                                                    const int* __restrict__ boff,
                                                    int* __restrict__ rowptr) {
    __shared__ int sd[256];
    int idx = blockIdx.x * 256 + threadIdx.x;
    int t = threadIdx.x;
    int v = (idx < N_NODES) ? cnt[idx] : 0;
    sd[t] = v;
    __syncthreads();
    for (int off = 1; off < 256; off <<= 1) {
        int u = (t >= off) ? sd[t - off] : 0;
        __syncthreads();
        sd[t] += u;
        __syncthreads();
    }
    if (idx < N_NODES) rowptr[idx] = sd[t] - v + boff[blockIdx.x];  // exclusive
    if (idx == 0) rowptr[N_NODES] = N_EDGES;
}

__global__ __launch_bounds__(256) void k_fill(const int* __restrict__ src,
                                              const int* __restrict__ dst,
                                              const int* __restrict__ rowptr,
                                              int* __restrict__ cur,
                                              int* __restrict__ csrc) {
    int e = blockIdx.x * 256 + threadIdx.x;   // grid = E/256 exact
    int d = dst[e];
    int pos = rowptr[d] + atomicAdd(&cur[d], 1);
    csrc[pos] = src[e];
}

// ---------------------------------------------------------------------------
// Conv 1 front: aggregate x (F_IN=2) and apply W1a (2x128) + bias + relu.
// ---------------------------------------------------------------------------

__global__ __launch_bounds__(256) void k_aggr0(const float2* __restrict__ x,
                                               const int* __restrict__ rowptr,
                                               const int* __restrict__ csrc,
                                               float2* __restrict__ t0) {
    int n = blockIdx.x * 256 + threadIdx.x;
    if (n >= N_NODES) return;
    int s = rowptr[n], e = rowptr[n + 1];
    float2 a0 = x[n];
    float2 a1 = make_float2(0.f, 0.f);
    int k = s;
    for (; k + 1 < e; k += 2) {
        float2 v0 = x[csrc[k]];
        float2 v1 = x[csrc[k + 1]];
        a0.x += v0.x; a0.y += v0.y;
        a1.x += v1.x; a1.y += v1.y;
    }
    if (k < e) { float2 v = x[csrc[k]]; a0.x += v.x; a0.y += v.y; }
    t0[n] = make_float2(a0.x + a1.x, a0.y + a1.y);
}

__global__ __launch_bounds__(256) void k_lin1a(const float2* __restrict__ t0,
                                               const float* __restrict__ W1a,
                                               const float* __restrict__ b1a,
                                               float* __restrict__ out) {
    int gid = blockIdx.x * 256 + threadIdx.x;   // grid = N*128/256 exact
    int n = gid >> 7, j = gid & 127;
    float2 t = t0[n];
    float v = fmaf(t.x, W1a[j], fmaf(t.y, W1a[128 + j], b1a[j]));
    out[gid] = fmaxf(v, 0.f);
}

// ---------------------------------------------------------------------------
// GIN aggregation, H=128, bf16 input: one wave per node, lane holds one uint
// (2 bf16 features). out[n] = h[n] + sum_{src in-edges} h[src]  (fp32 accum)
// ---------------------------------------------------------------------------

__global__ __launch_bounds__(256) void k_aggr128_bf16(const uint* __restrict__ hb,
                                                      const int* __restrict__ rowptr,
                                                      const int* __restrict__ csrc,
                                                      float2* __restrict__ out) {
    int node = blockIdx.x * 4 + (threadIdx.x >> 6);   // grid = N/4 exact
    int lane = threadIdx.x & 63;
    int s = rowptr[node], e = rowptr[node + 1];
    uint sv = hb[(size_t)node * 64 + lane];
    float ax0 = bflo(sv), ay0 = bfhi(sv);
    float ax1 = 0.f, ay1 = 0.f, ax2 = 0.f, ay2 = 0.f, ax3 = 0.f, ay3 = 0.f;
    for (int base = s; base < e; base += 64) {
        int cnt = e - base; if (cnt > 64) cnt = 64;
        int idx = csrc[base + ((lane < cnt) ? lane : 0)];   // coalesced list load
        int j = 0;
        for (; j + 3 < cnt; j += 4) {
            int s0 = __shfl(idx, j),     s1 = __shfl(idx, j + 1);
            int s2 = __shfl(idx, j + 2), s3 = __shfl(idx, j + 3);
            uint v0 = hb[(size_t)s0 * 64 + lane];
            uint v1 = hb[(size_t)s1 * 64 + lane];
            uint v2 = hb[(size_t)s2 * 64 + lane];
            uint v3 = hb[(size_t)s3 * 64 + lane];
            ax0 += bflo(v0); ay0 += bfhi(v0);
            ax1 += bflo(v1); ay1 += bfhi(v1);
            ax2 += bflo(v2); ay2 += bfhi(v2);
            ax3 += bflo(v3); ay3 += bfhi(v3);
        }
        for (; j < cnt; ++j) {
            int sj = __shfl(idx, j);
            uint v = hb[(size_t)sj * 64 + lane];
            ax0 += bflo(v); ay0 += bfhi(v);
        }
    }
    out[(size_t)node * 64 + lane] =
        make_float2((ax0 + ax1) + (ax2 + ax3), (ay0 + ay1) + (ay2 + ay3));
}

// ---------------------------------------------------------------------------
// fp32 GEMM: C[n][j] = relu(sum_k A[n][k] * W[k][j] + bias[j]), K=128, cols=128.
// 128-row tile per block, k-chunks of 32 in LDS, 8x8 micro-tile per thread.
// OUT_BF16: epilogue packs to bf16 (uint-packed pairs). In-place safe when
// !OUT_BF16 and C==A (block reads only its own rows, all before epilogue).
// ---------------------------------------------------------------------------

template <bool OUT_BF16>
__global__ __launch_bounds__(256) void k_gemm128(const float* A,
                                                 const float* __restrict__ W,
                                                 const float* __restrict__ bias,
                                                 void* Cv, int nrows) {
    __shared__ float As[32][128];   // k-major: As[kk][row]
    __shared__ float Ws[32][128];   // k-major: Ws[kk][col]
    const int tid = threadIdx.x;
    const int tx = tid & 15;        // col group: cols 8*tx..8*tx+7
    const int ty = tid >> 4;        // row group: rows 8*ty..8*ty+7
    const int rowBase = blockIdx.x << 7;
    float acc[8][8];
#pragma unroll
    for (int i = 0; i < 8; ++i)
#pragma unroll
        for (int j = 0; j < 8; ++j) acc[i][j] = 0.f;

    const int r  = tid >> 1;          // staging row (0..127)
    const int k0 = (tid & 1) << 4;    // staging k half (0 or 16)
    const int grow = rowBase + r;

    for (int kc = 0; kc < 128; kc += 32) {
        float4 av[4];
        if (grow < nrows) {
            const float4* Ap = (const float4*)(A + (size_t)grow * 128 + kc + k0);
#pragma unroll
            for (int q = 0; q < 4; ++q) av[q] = Ap[q];
        } else {
#pragma unroll
            for (int q = 0; q < 4; ++q) av[q] = make_float4(0.f, 0.f, 0.f, 0.f);
        }
        float4 wv[4];
        const float4* Wp = (const float4*)(W + (size_t)kc * 128);
#pragma unroll
        for (int q = 0; q < 4; ++q) wv[q] = Wp[tid * 4 + q];
        __syncthreads();   // previous chunk's compute done before overwrite
#pragma unroll
        for (int q = 0; q < 4; ++q) {   // transpose A into k-major
            As[k0 + q * 4 + 0][r] = av[q].x;
            As[k0 + q * 4 + 1][r] = av[q].y;
            As[k0 + q * 4 + 2][r] = av[q].z;
            As[k0 + q * 4 + 3][r] = av[q].w;
        }
#pragma unroll
        for (int q = 0; q < 4; ++q) ((float4*)Ws)[tid * 4 + q] = wv[q];
        __syncthreads();
#pragma unroll 4
        for (int kk = 0; kk < 32; ++kk) {
            float a[8], w[8];
            *(float4*)&a[0] = *(const float4*)&As[kk][ty * 8];
            *(float4*)&a[4] = *(const float4*)&As[kk][ty * 8 + 4];
            *(float4*)&w[0] = *(const float4*)&Ws[kk][tx * 8];
            *(float4*)&w[4] = *(const float4*)&Ws[kk][tx * 8 + 4];
#pragma unroll
            for (int i = 0; i < 8; ++i)
#pragma unroll
                for (int j = 0; j < 8; ++j)
                    acc[i][j] = fmaf(a[i], w[j], acc[i][j]);
        }
    }
    float bv[8];
#pragma unroll
    for (int j = 0; j < 8; ++j) bv[j] = bias[tx * 8 + j];
#pragma unroll
    for (int i = 0; i < 8; ++i) {
        int row = rowBase + ty * 8 + i;
        if (row < nrows) {
            float o[8];
#pragma unroll
            for (int j = 0; j < 8; ++j) o[j] = fmaxf(acc[i][j] + bv[j], 0.f);
            if (OUT_BF16) {
                uint4 pk;
                pk.x = packbf(o[0], o[1]);
                pk.y = packbf(o[2], o[3]);
                pk.z = packbf(o[4], o[5]);
                pk.w = packbf(o[6], o[7]);
                *(uint4*)((ushort*)Cv + (size_t)row * 128 + tx * 8) = pk;
            } else {
                float* C = (float*)Cv;
                *(float4*)(C + (size_t)row * 128 + tx * 8)     = *(float4*)&o[0];
                *(float4*)(C + (size_t)row * 128 + tx * 8 + 4) = *(float4*)&o[4];
            }
        }
    }
}

// ---------------------------------------------------------------------------
// Pooling: node -> subgraph -> graph (atomic fadd, accumulators L2-resident).
// ---------------------------------------------------------------------------

__global__ __launch_bounds__(256) void k_pool1(const uint* __restrict__ hb,
                                               const int* __restrict__ n2s,
                                               float* __restrict__ poolS) {
    int gid = blockIdx.x * 256 + threadIdx.x;   // grid = N*64/256 exact
    int n = gid >> 6, c = gid & 63;
    uint v = hb[gid];
    int sg = n2s[n];
    atomicAdd(&poolS[(size_t)sg * 128 + 2 * c],     bflo(v));
    atomicAdd(&poolS[(size_t)sg * 128 + 2 * c + 1], bfhi(v));
}

__global__ __launch_bounds__(256) void k_pool2(const float* __restrict__ poolS,
                                               const int* __restrict__ s2g,
                                               float* __restrict__ poolG) {
    int gid = blockIdx.x * 256 + threadIdx.x;   // grid = S*128/256 exact
    int s = gid >> 7, j = gid & 127;
    atomicAdd(&poolG[(size_t)s2g[s] * 128 + j], poolS[gid]);
}

// ---------------------------------------------------------------------------
// Final MLP + log_softmax: one block per graph (G=64), 128 threads.
// ---------------------------------------------------------------------------

__global__ __launch_bounds__(128) void k_final(const float* __restrict__ poolG,
                                               const float* __restrict__ W1,
                                               const float* __restrict__ b1,
                                               const float* __restrict__ W2,
                                               const float* __restrict__ b2,
                                               float* __restrict__ out) {
    __shared__ float row[128];
    __shared__ float t1[128];
    __shared__ float red[128];
    int g = blockIdx.x, j = threadIdx.x;
    row[j] = poolG[g * 128 + j];
    __syncthreads();
    float s = b1[j];
    for (int k = 0; k < 128; ++k) s = fmaf(row[k], W1[k * 128 + j], s);
    t1[j] = fmaxf(s, 0.f);
    __syncthreads();
    float s2 = b2[j];
    for (int k = 0; k < 128; ++k) s2 = fmaf(t1[k], W2[k * 128 + j], s2);
    red[j] = s2;
    __syncthreads();
    for (int off = 64; off > 0; off >>= 1) {
        if (j < off) red[j] = fmaxf(red[j], red[j + off]);
        __syncthreads();
    }
    float m = red[0];
    __syncthreads();
    red[j] = expf(s2 - m);
    __syncthreads();
    for (int off = 64; off > 0; off >>= 1) {
        if (j < off) red[j] += red[j + off];
        __syncthreads();
    }
    float lse = m + logf(red[0]);
    out[g * 128 + j] = s2 - lse;
}

// ---------------------------------------------------------------------------

extern "C" void kernel_launch(void* const* d_in, const int* in_sizes, int n_in,
                              void* d_out, int out_size, void* d_ws, size_t ws_size,
                              hipStream_t stream) {
    (void)in_sizes; (void)n_in; (void)out_size; (void)ws_size;
    const float* x    = (const float*)d_in[0];
    const int*   ei   = (const int*)d_in[1];
    const int*   n2s  = (const int*)d_in[2];
    const int*   s2g  = (const int*)d_in[3];
    const float* W1a  = (const float*)d_in[4];
    const float* b1a  = (const float*)d_in[5];
    const float* W1b  = (const float*)d_in[6];
    const float* b1b  = (const float*)d_in[7];
    const float* cWa  = (const float*)d_in[8];
    const float* cba  = (const float*)d_in[9];
    const float* cWb  = (const float*)d_in[10];
    const float* cbb  = (const float*)d_in[11];
    const float* l1W  = (const float*)d_in[12];
    const float* l1b  = (const float*)d_in[13];
    const float* l2W  = (const float*)d_in[14];
    const float* l2b  = (const float*)d_in[15];
    float* out = (float*)d_out;

    // workspace layout (~45 MB)
    float* aggrF  = (float*)d_ws;                       // N*128 fp32 (aggr out / gemmA in-place)
    uint*  hb     = (uint*)(aggrF + (size_t)N_NODES * HDIM); // N*64 uints (bf16 h)
    float* t0     = (float*)(hb + (size_t)N_NODES * 64);     // N*2 fp32
    int*   rowptr = (int*)(t0 + (size_t)N_NODES * 2);   // N+2 (padded)
    int*   cnt    = rowptr + (N_NODES + 2);             // N
    int*   bsum   = cnt + N_NODES;                      // 256
    int*   boff   = bsum + 256;                         // 256
    int*   csrc   = boff + 256;                         // E
    float* poolS  = (float*)(csrc + N_EDGES);           // S*128
    float* poolG  = poolS + (size_t)SSUB * HDIM;        // G*128

    const int* srcA = ei;
    const int* dstA = ei + N_EDGES;
    const int nScanBlocks = (N_NODES + 255) / 256;      // 196
    const int nGemmBlocks = (N_NODES + 127) / 128;      // 391

    // --- CSR build ---
    hipMemsetAsync(cnt, 0, N_NODES * sizeof(int), stream);
    hipMemsetAsync(poolS, 0, (size_t)(SSUB + GGRAPH) * HDIM * sizeof(float), stream);
    k_hist<<<N_EDGES / 256, 256, 0, stream>>>(dstA, cnt);
    k_scan_reduce<<<nScanBlocks, 256, 0, stream>>>(cnt, bsum);
    k_scan_top<<<1, 256, 0, stream>>>(bsum, boff, nScanBlocks);
    k_scan_final<<<nScanBlocks, 256, 0, stream>>>(cnt, boff, rowptr);
    hipMemsetAsync(cnt, 0, N_NODES * sizeof(int), stream);
    k_fill<<<N_EDGES / 256, 256, 0, stream>>>(srcA, dstA, rowptr, cnt, csrc);

    // --- conv 1: aggr(x) -> lin1a -> gemm(W1b) -> bf16 h ---
    k_aggr0<<<nScanBlocks, 256, 0, stream>>>((const float2*)x, rowptr, csrc, (float2*)t0);
    k_lin1a<<<(N_NODES * HDIM) / 256, 256, 0, stream>>>((const float2*)t0, W1a, b1a, aggrF);
    k_gemm128<true><<<nGemmBlocks, 256, 0, stream>>>(aggrF, W1b, b1b, hb, N_NODES);

    // --- convs 2..4: aggr(bf16 h) -> gemmA (in-place fp32) -> gemmB (-> bf16 h) ---
    for (int i = 0; i < 3; ++i) {
        k_aggr128_bf16<<<N_NODES / 4, 256, 0, stream>>>(hb, rowptr, csrc, (float2*)aggrF);
        k_gemm128<false><<<nGemmBlocks, 256, 0, stream>>>(aggrF, cWa + (size_t)i * HDIM * HDIM,
                                                          cba + i * HDIM, aggrF, N_NODES);
        k_gemm128<true><<<nGemmBlocks, 256, 0, stream>>>(aggrF, cWb + (size_t)i * HDIM * HDIM,
                                                         cbb + i * HDIM, hb, N_NODES);
    }

    // --- pooling + head ---
    k_pool1<<<(N_NODES * 64) / 256, 256, 0, stream>>>(hb, n2s, poolS);
    k_pool2<<<(SSUB * HDIM) / 256, 256, 0, stream>>>(poolS, s2g, poolG);
    k_final<<<GGRAPH, 128, 0, stream>>>(poolG, l1W, l1b, l2W, l2b, out);
}